// Round 5
// baseline (473.574 us; speedup 1.0000x reference)
//
#include <hip/hip_runtime.h>
#include <hip/hip_bf16.h>

#define NN 100000
#define NE 1600000
#define CIN 64
#define HIDN 32
#define NG 128
#define SLOPE 0.01f

// ---------------- CSR build: one atomic pass producing ranks (split in halves) ----------------

__global__ __launch_bounds__(256) void k_rank(const int* __restrict__ dst,
                                              int* __restrict__ deg,
                                              int* __restrict__ rank,
                                              int qbase, int qcount) {
  int i0 = blockIdx.x * 256 + threadIdx.x;
  if (i0 >= qcount) return;
  int i = qbase + i0;
  int4 d = ((const int4*)dst)[i];
  int4 r;
  r.x = atomicAdd(&deg[d.x], 1);
  r.y = atomicAdd(&deg[d.y], 1);
  r.z = atomicAdd(&deg[d.z], 1);
  r.w = atomicAdd(&deg[d.w], 1);
  ((int4*)rank)[i] = r;
}

// ---------------- prefix scan (3-kernel), 1024 items/block ----------------

__global__ __launch_bounds__(256) void k_scan1(const int* __restrict__ deg,
                                               int* __restrict__ bsum) {
  __shared__ int s[256];
  int t = threadIdx.x;
  int base = blockIdx.x * 1024 + t * 4;
  int sum = 0;
#pragma unroll
  for (int j = 0; j < 4; ++j) {
    int idx = base + j;
    if (idx < NN) sum += deg[idx];
  }
  s[t] = sum;
  __syncthreads();
  for (int o = 128; o > 0; o >>= 1) {
    if (t < o) s[t] += s[t + o];
    __syncthreads();
  }
  if (t == 0) bsum[blockIdx.x] = s[0];
}

// middle scan + group counts (batch sorted -> binary-search boundaries), one block of 256
__global__ __launch_bounds__(256) void k_mid(int* __restrict__ bsum,
                                             int* __restrict__ rowp,
                                             const int* __restrict__ batch,
                                             float* __restrict__ cinv, int nblk) {
  __shared__ int s[128];
  __shared__ int sb[NG + 1];
  int t = threadIdx.x;
  if (t < nblk) s[t] = bsum[t];
  if (t <= NG) {
    int lo = 0, hi = NN;  // lower_bound of t
    while (lo < hi) {
      int mid = (lo + hi) >> 1;
      if (batch[mid] < t) lo = mid + 1; else hi = mid;
    }
    sb[t] = lo;
  }
  __syncthreads();
  if (t == 0) {
    int run = 0;
    for (int i = 0; i < nblk; ++i) {
      int v = s[i];
      s[i] = run;
      run += v;
    }
    rowp[NN] = run;  // == NE
  }
  __syncthreads();
  if (t < nblk) bsum[t] = s[t];
  if (t < NG) {
    int c = sb[t + 1] - sb[t];
    cinv[t] = 1.0f / (3.0f * fmaxf((float)c, 1.0f));
  }
}

// scan3 + dinv fused (deg values already in registers)
__global__ __launch_bounds__(256) void k_scan3(const int* __restrict__ deg,
                                               const int* __restrict__ bsum,
                                               int* __restrict__ rowp,
                                               float* __restrict__ dinv) {
  __shared__ int s[256];
  int t = threadIdx.x;
  int base = blockIdx.x * 1024 + t * 4;
  int d0 = 0, d1 = 0, d2 = 0, d3 = 0;
  if (base < NN) d0 = deg[base];
  if (base + 1 < NN) d1 = deg[base + 1];
  if (base + 2 < NN) d2 = deg[base + 2];
  if (base + 3 < NN) d3 = deg[base + 3];
  int ts = d0 + d1 + d2 + d3;
  s[t] = ts;
  __syncthreads();
  for (int o = 1; o < 256; o <<= 1) {
    int v = (t >= o) ? s[t - o] : 0;
    __syncthreads();
    s[t] += v;
    __syncthreads();
  }
  int run = bsum[blockIdx.x] + s[t] - ts;  // exclusive prefix for this thread
  if (base < NN) { rowp[base] = run; dinv[base] = rsqrtf((float)d0 + 1.0f); run += d0; }
  if (base + 1 < NN) { rowp[base + 1] = run; dinv[base + 1] = rsqrtf((float)d1 + 1.0f); run += d1; }
  if (base + 2 < NN) { rowp[base + 2] = run; dinv[base + 2] = rsqrtf((float)d2 + 1.0f); run += d2; }
  if (base + 3 < NN) { rowp[base + 3] = run; dinv[base + 3] = rsqrtf((float)d3 + 1.0f); run += d3; }
}

// no atomics: position = rowp[dst] + precomputed rank (split in halves)
__global__ __launch_bounds__(256) void k_scatter(const int* __restrict__ src,
                                                 const int* __restrict__ dst,
                                                 const int* __restrict__ rank,
                                                 const int* __restrict__ rowp,
                                                 int* __restrict__ col,
                                                 int qbase, int qcount) {
  int i0 = blockIdx.x * 256 + threadIdx.x;
  if (i0 >= qcount) return;
  int i = qbase + i0;
  int4 d = ((const int4*)dst)[i];
  int4 r = ((const int4*)rank)[i];
  int4 s = ((const int4*)src)[i];
  col[rowp[d.x] + r.x] = s.x;
  col[rowp[d.y] + r.y] = s.y;
  col[rowp[d.z] + r.z] = s.z;
  col[rowp[d.w] + r.w] = s.w;
}

// ---------------- dense hs = bf16( dinv ⊙ (in @ W) ) ----------------

template <int K>
__global__ __launch_bounds__(256) void k_mm(const float* __restrict__ in,
                                            const float* __restrict__ W,
                                            const float* __restrict__ dinv,
                                            __hip_bfloat16* __restrict__ out) {
  __shared__ float sW[K * HIDN];
  int t = threadIdx.x;
  for (int i = t; i < K * HIDN; i += 256) sW[i] = W[i];
  __syncthreads();
  int gid = blockIdx.x * 256 + t;
  int node = gid >> 5;
  int f = gid & 31;
  if (node >= NN) return;
  const float* xr = in + node * K;
  float acc = 0.f;
#pragma unroll
  for (int k = 0; k < K; ++k) acc += xr[k] * sW[k * HIDN + f];
  out[node * HIDN + f] = __float2bfloat16(acc * dinv[node]);
}

// ---------------- CSR aggregation + bias + leakyReLU + fused mean-pool ----------------
// hs rows are bf16, pre-scaled by dinv: agg_i = dinv_i * (hs_i + sum_c hs_c)
// Latency-bound gather: unroll 8 for MLP; col marked non-temporal.

template <int WRITE_H>
__global__ __launch_bounds__(256) void k_agg(const __hip_bfloat16* __restrict__ hs,
                                             const int* __restrict__ rowp,
                                             const int* __restrict__ col,
                                             const float* __restrict__ dinv,
                                             const int* __restrict__ batch,
                                             const float* __restrict__ cinv,
                                             const float* __restrict__ bias,
                                             float* __restrict__ hout,
                                             float* __restrict__ pool) {
  const int t = threadIdx.x;
  const int f = t & 31;
  const int sub = t >> 5;  // 0..7
  const float bf = bias[f];
  float pacc = 0.f;
  int gcur = -1;
  const int base = blockIdx.x * 32;
#pragma unroll
  for (int it = 0; it < 4; ++it) {
    const int i = base + it * 8 + sub;
    if (i < NN) {
      float acc = __bfloat162float(hs[i * HIDN + f]);  // self-loop term
      const int rs = rowp[i];
      const int re = rowp[i + 1];
      int e = rs;
      for (; e + 8 <= re; e += 8) {
        const int c0 = __builtin_nontemporal_load(col + e);
        const int c1 = __builtin_nontemporal_load(col + e + 1);
        const int c2 = __builtin_nontemporal_load(col + e + 2);
        const int c3 = __builtin_nontemporal_load(col + e + 3);
        const int c4 = __builtin_nontemporal_load(col + e + 4);
        const int c5 = __builtin_nontemporal_load(col + e + 5);
        const int c6 = __builtin_nontemporal_load(col + e + 6);
        const int c7 = __builtin_nontemporal_load(col + e + 7);
        const float v0 = __bfloat162float(hs[c0 * HIDN + f]);
        const float v1 = __bfloat162float(hs[c1 * HIDN + f]);
        const float v2 = __bfloat162float(hs[c2 * HIDN + f]);
        const float v3 = __bfloat162float(hs[c3 * HIDN + f]);
        const float v4 = __bfloat162float(hs[c4 * HIDN + f]);
        const float v5 = __bfloat162float(hs[c5 * HIDN + f]);
        const float v6 = __bfloat162float(hs[c6 * HIDN + f]);
        const float v7 = __bfloat162float(hs[c7 * HIDN + f]);
        acc += ((v0 + v1) + (v2 + v3)) + ((v4 + v5) + (v6 + v7));
      }
      for (; e + 4 <= re; e += 4) {
        const int c0 = __builtin_nontemporal_load(col + e);
        const int c1 = __builtin_nontemporal_load(col + e + 1);
        const int c2 = __builtin_nontemporal_load(col + e + 2);
        const int c3 = __builtin_nontemporal_load(col + e + 3);
        const float v0 = __bfloat162float(hs[c0 * HIDN + f]);
        const float v1 = __bfloat162float(hs[c1 * HIDN + f]);
        const float v2 = __bfloat162float(hs[c2 * HIDN + f]);
        const float v3 = __bfloat162float(hs[c3 * HIDN + f]);
        acc += (v0 + v1) + (v2 + v3);
      }
      for (; e < re; ++e) acc += __bfloat162float(hs[col[e] * HIDN + f]);
      float v = acc * dinv[i] + bf;
      v = v > 0.f ? v : SLOPE * v;
      if (WRITE_H) hout[i * HIDN + f] = v;
      const int g = batch[i];
      if (g != gcur) {
        if (gcur >= 0) unsafeAtomicAdd(&pool[gcur * HIDN + f], pacc * cinv[gcur]);
        gcur = g;
        pacc = 0.f;
      }
      pacc += v;
    }
  }
  if (gcur >= 0) unsafeAtomicAdd(&pool[gcur * HIDN + f], pacc * cinv[gcur]);
}

// ---------------- launch ----------------

extern "C" void kernel_launch(void* const* d_in, const int* in_sizes, int n_in,
                              void* d_out, int out_size, void* d_ws, size_t ws_size,
                              hipStream_t stream) {
  const float* x = (const float*)d_in[0];
  const float* W0 = (const float*)d_in[1];
  const float* b0 = (const float*)d_in[2];
  const float* W1 = (const float*)d_in[3];
  const float* b1 = (const float*)d_in[4];
  const float* W2 = (const float*)d_in[5];
  const float* b2 = (const float*)d_in[6];
  const int* src = (const int*)d_in[7];
  const int* dst = (const int*)d_in[8];
  const int* batch = (const int*)d_in[9];
  float* out = (float*)d_out;

  char* ws = (char*)d_ws;
  auto carve = [&](size_t bytes) -> char* {
    char* p = ws;
    ws += (bytes + 255) & ~(size_t)255;
    return p;
  };
  int* deg = (int*)carve(NN * 4);
  int* rank = (int*)carve((size_t)NE * 4);
  int* rowp = (int*)carve((NN + 1) * 4);
  int* bsum = (int*)carve(128 * 4);
  float* dinv = (float*)carve(NN * 4);
  float* cinv = (float*)carve(NG * 4);
  int* col = (int*)carve((size_t)NE * 4);
  float* hA = (float*)carve((size_t)NN * HIDN * 4);
  __hip_bfloat16* hs = (__hip_bfloat16*)carve((size_t)NN * HIDN * 2);

  hipMemsetAsync(deg, 0, NN * 4, stream);
  hipMemsetAsync(out, 0, NG * HIDN * 4, stream);

  const int QH = NE / 4 / 2;                 // 200000 quads per half
  const int half_grid = (QH + 255) / 256;    // 782
  k_rank<<<half_grid, 256, 0, stream>>>(dst, deg, rank, 0, QH);
  k_rank<<<half_grid, 256, 0, stream>>>(dst, deg, rank, QH, QH);

  int nblk = (NN + 1023) / 1024;  // 98
  k_scan1<<<nblk, 256, 0, stream>>>(deg, bsum);
  k_mid<<<1, 256, 0, stream>>>(bsum, rowp, batch, cinv, nblk);
  k_scan3<<<nblk, 256, 0, stream>>>(deg, bsum, rowp, dinv);

  k_scatter<<<half_grid, 256, 0, stream>>>(src, dst, rank, rowp, col, 0, QH);
  k_scatter<<<half_grid, 256, 0, stream>>>(src, dst, rank, rowp, col, QH, QH);

  const int mm_grid = (NN * HIDN + 255) / 256;  // 12500
  const int agg_grid = (NN + 31) / 32;          // 3125

  // layer 0
  k_mm<CIN><<<mm_grid, 256, 0, stream>>>(x, W0, dinv, hs);
  k_agg<1><<<agg_grid, 256, 0, stream>>>(hs, rowp, col, dinv, batch, cinv, b0, hA, out);
  // layer 1
  k_mm<HIDN><<<mm_grid, 256, 0, stream>>>(hA, W1, dinv, hs);
  k_agg<1><<<agg_grid, 256, 0, stream>>>(hs, rowp, col, dinv, batch, cinv, b1, hA, out);
  // layer 2 (pool only; hout never consumed)
  k_mm<HIDN><<<mm_grid, 256, 0, stream>>>(hA, W2, dinv, hs);
  k_agg<0><<<agg_grid, 256, 0, stream>>>(hs, rowp, col, dinv, batch, cinv, b2, hA, out);
}